// Round 17
// baseline (62.544 us; speedup 1.0000x reference)
//
#include <hip/hip_runtime.h>
#include <hip/hip_bf16.h>
#include <math.h>

#define BB 4
#define CC 256
#define NN 4096   // H*W
#define EE 32     // embedding channels

typedef __attribute__((ext_vector_type(8))) short bf16x8;    // 8 bf16 = 4 VGPR
typedef __attribute__((ext_vector_type(4))) float f32x4;
typedef __attribute__((ext_vector_type(16))) float f32x16;
typedef __attribute__((ext_vector_type(2))) unsigned uint32x2_t;

__device__ inline unsigned short f2bf(float x) {
    union { __hip_bfloat16 h; unsigned short u; } cv;
    cv.h = __float2bfloat16(x);
    return cv.u;
}
__device__ inline unsigned pk2(float lo, float hi) {
    return ((unsigned)f2bf(hi) << 16) | (unsigned)f2bf(lo);
}
__device__ inline float fexp2(float x) { return __builtin_amdgcn_exp2f(x); }
__device__ inline unsigned cvtpk(float lo, float hi) {
    unsigned r;
    asm("v_cvt_pk_bf16_f32 %0, %1, %2" : "=v"(r) : "v"(lo), "v"(hi));
    return r;
}
__device__ inline float bflo(unsigned u) {
    union { unsigned v; float f; } c; c.v = u << 16; return c.f;
}
__device__ inline float bfhi(unsigned u) {
    union { unsigned v; float f; } c; c.v = u & 0xFFFF0000u; return c.f;
}

// ---------------------------------------------------------------------------
// K0: one-time weight convert. wB rows 0-31 = kw, 32-63 = qw*log2e, 64-95 = vw.
// ---------------------------------------------------------------------------
__global__ __launch_bounds__(256) void wcvt_kernel(
    const float* __restrict__ kw, const float* __restrict__ kb,
    const float* __restrict__ qw, const float* __restrict__ qb,
    const float* __restrict__ vw, const float* __restrict__ vb,
    __hip_bfloat16* __restrict__ wB, float* __restrict__ bB)
{
    int r = blockIdx.x;            // 0..95
    int t = threadIdx.x;
    int rr = r & 31;
    const float* src; float scale = 1.f;
    if (r < 32)      src = kw;
    else if (r < 64) { src = qw; scale = 1.44269504f; }
    else             src = vw;
    if (t < 64) {
        float4 v = *(const float4*)(src + rr * 256 + t * 4);
        uint2 p;
        p.x = pk2(v.x * scale, v.y * scale);
        p.y = pk2(v.z * scale, v.w * scale);
        *(uint2*)((unsigned short*)wB + r * 256 + t * 4) = p;
    }
    if (r == 0 && t >= 64 && t < 160) {
        int e = t - 64;
        const float* bs = (e < 32) ? kb : ((e < 64) ? qb : vb);
        float sc = (e >= 32 && e < 64) ? 1.44269504f : 1.f;
        bB[e] = bs[e & 31] * sc;
    }
}

// ---------------------------------------------------------------------------
// K1: MFMA QKV projection (x read once, all 96 channels).
//   fT/gT: [B][N][32]   hT: TILED [B][N/32][32e][32k]
// grid = B*(N/32) = 512, block = 256.
// ---------------------------------------------------------------------------
__global__ __launch_bounds__(256) void proj_kernel(
    const float* __restrict__ x,
    const __hip_bfloat16* __restrict__ wB, const float* __restrict__ bB,
    __hip_bfloat16* __restrict__ fT, __hip_bfloat16* __restrict__ gT,
    __hip_bfloat16* __restrict__ hT)
{
    __shared__ unsigned xs[32][132];   // stride 132 u32: b128 reads conflict-free
    int b     = blockIdx.x >> 7;
    int ibase = (blockIdx.x & 127) << 5;

    // staging: thread t loads x[c][i4..i4+3] for 8 c-pairs (coalesced float4)
    int t   = threadIdx.x;
    int ig4 = (t & 7) * 4;          // i offset 0..28
    int crw = t >> 3;               // c-row slot 0..31
    const float* xb = x + (size_t)b * CC * NN + ibase;
#pragma unroll
    for (int it = 0; it < 4; ++it) {
        int cp = it * 32 + crw;     // c-pair 0..127
        float4 fa = *(const float4*)(xb + (size_t)(2 * cp) * NN + ig4);
        float4 fc = *(const float4*)(xb + (size_t)(2 * cp + 1) * NN + ig4);
        xs[ig4 + 0][cp] = pk2(fa.x, fc.x);
        xs[ig4 + 1][cp] = pk2(fa.y, fc.y);
        xs[ig4 + 2][cp] = pk2(fa.z, fc.z);
        xs[ig4 + 3][cp] = pk2(fa.w, fc.w);
    }
    __syncthreads();

    int wv = threadIdx.x >> 6;
    int l  = threadIdx.x & 63;
    int q15  = l & 15, g = l >> 4;
    int isub = wv & 1, eh = wv >> 1;
    int irow = (isub << 4) + q15;
    const __hip_bfloat16* w0 = wB + ((size_t)(eh * 48) + q15) * 256;

    f32x4 a0 = {0,0,0,0}, a1 = {0,0,0,0}, a2 = {0,0,0,0};
#pragma unroll
    for (int kk = 0; kk < 8; ++kk) {
        bf16x8 Bf = *(const bf16x8*)&xs[irow][kk * 16 + 4 * g];
        int co = kk * 32 + 8 * g;
        bf16x8 A0 = *(const bf16x8*)(w0 + co);
        bf16x8 A1 = *(const bf16x8*)(w0 + 16 * 256 + co);
        bf16x8 A2 = *(const bf16x8*)(w0 + 32 * 256 + co);
        a0 = __builtin_amdgcn_mfma_f32_16x16x32_bf16(A0, Bf, a0, 0, 0, 0);
        a1 = __builtin_amdgcn_mfma_f32_16x16x32_bf16(A1, Bf, a1, 0, 0, 0);
        a2 = __builtin_amdgcn_mfma_f32_16x16x32_bf16(A2, Bf, a2, 0, 0, 0);
    }

    int ig = ibase + irow;
    auto emit = [&](f32x4 acc, int T) {
        float4 bb = *(const float4*)(bB + T * 16 + 4 * g);
        float d0 = acc[0] + bb.x, d1 = acc[1] + bb.y;
        float d2 = acc[2] + bb.z, d3 = acc[3] + bb.w;
        if (T < 4) {
            __hip_bfloat16* dst = (T < 2) ? fT : gT;
            int eoff = ((T & 1) << 4) + 4 * g;
            uint2 pq; pq.x = pk2(d0, d1); pq.y = pk2(d2, d3);
            *(uint2*)((unsigned short*)dst + ((size_t)b * NN + ig) * EE + eoff) = pq;
        } else {
            unsigned short* dst = (unsigned short*)hT;
            int e  = ((T - 4) << 4) + 4 * g;
            int kt = ig >> 5, kk2 = ig & 31;
            size_t base = ((size_t)(b * 128 + kt) * 32 + e) * 32 + kk2;
            dst[base]       = f2bf(d0);
            dst[base + 32]  = f2bf(d1);
            dst[base + 64]  = f2bf(d2);
            dst[base + 96]  = f2bf(d3);
        }
    };
    emit(a0, eh * 3 + 0);
    emit(a1, eh * 3 + 1);
    emit(a2, eh * 3 + 2);
}

// ---------------------------------------------------------------------------
// K2: attention pass 1 (split-K), OCCUPANCY round: 32 queries/wave (one
// q-set), 8 waves/SIMD (grid 1024 = 4 blocks/CU, VGPR<=64 via launch
// bounds). Block = 256 queries x 256 keys; 8 waves share one 32KB K/V
// slice. K prefetched one chunk ahead; V loaded on demand (L1-hot, TLP
// hides it). S MFMAs chained (reg pressure; 8-wave TLP covers the chain).
// NO setprio (r14). Fixed m=0 softmax -> pure-sum partials, plain stores.
// part: [B*16kt][N][32] bf16  lpart: [B*16kt][N] f32  (same layout as r15)
// grid = B * 16qt * 16kt = 1024, block = 512, 8 waves/EU.
// ---------------------------------------------------------------------------
__global__ __launch_bounds__(512, 8) void attn_kernel(
    const __hip_bfloat16* __restrict__ fT,
    const __hip_bfloat16* __restrict__ gT,
    const __hip_bfloat16* __restrict__ hT,
    unsigned short* __restrict__ part, float* __restrict__ lpart)
{
    int blk   = blockIdx.x;
    int b     = blk >> 8;
    int qt    = (blk >> 4) & 15;     // query tile (256 q)
    int kt    = blk & 15;            // key tile (256 k)
    int wv    = threadIdx.x >> 6;    // q-subtile 0..7 (32 q each)
    int lane  = threadIdx.x & 63;
    int q     = lane & 31;
    int h     = lane >> 5;           // key-half
    int qbase = qt * 256 + wv * 32;

    const __hip_bfloat16* fb = fT + (size_t)b * NN * EE;
    const __hip_bfloat16* gb = gT + (size_t)b * NN * EE;
    const __hip_bfloat16* hb = hT + (size_t)b * NN * EE + q * 32 + 8 * h; // e=q

    bf16x8 Qa0 = *(const bf16x8*)(gb + (size_t)(qbase + q) * EE + 8 * h);
    bf16x8 Qa1 = *(const bf16x8*)(gb + (size_t)(qbase + q) * EE + 16 + 8 * h);

    float lA = 0.f;
    f32x16 OA = {0,0,0,0,0,0,0,0,0,0,0,0,0,0,0,0};
    const f32x16 z16 = {0,0,0,0,0,0,0,0,0,0,0,0,0,0,0,0};

    int k0 = kt * 256;
    bf16x8 K0 = *(const bf16x8*)(fb + (size_t)(k0 + q) * EE + 8 * h);
    bf16x8 K1 = *(const bf16x8*)(fb + (size_t)(k0 + q) * EE + 16 + 8 * h);

    for (int c = 0; c < 8; ++c) {
        int kn = (k0 + 32) & (NN - 1);   // last prefetch clamped into range
        bf16x8 nK0 = *(const bf16x8*)(fb + (size_t)(kn + q) * EE + 8 * h);
        bf16x8 nK1 = *(const bf16x8*)(fb + (size_t)(kn + q) * EE + 16 + 8 * h);
        bf16x8 V0  = *(const bf16x8*)(hb + (size_t)k0 * 32);       // L1-hot
        bf16x8 V1  = *(const bf16x8*)(hb + (size_t)k0 * 32 + 16);

        f32x16 SA = __builtin_amdgcn_mfma_f32_32x32x16_bf16(K0, Qa0, z16, 0, 0, 0);
        SA = __builtin_amdgcn_mfma_f32_32x32x16_bf16(K1, Qa1, SA, 0, 0, 0);

        float p[16];
#pragma unroll
        for (int r = 0; r < 16; ++r) p[r] = fexp2(SA[r]);
        lA += ((p[0]+p[1])+(p[2]+p[3])) + ((p[4]+p[5])+(p[6]+p[7]))
            + ((p[8]+p[9])+(p[10]+p[11])) + ((p[12]+p[13])+(p[14]+p[15]));

        unsigned j0 = cvtpk(p[0], p[1]),   j1 = cvtpk(p[2], p[3]);
        unsigned j2 = cvtpk(p[4], p[5]),   j3 = cvtpk(p[6], p[7]);
        unsigned j4 = cvtpk(p[8], p[9]),   j5 = cvtpk(p[10], p[11]);
        unsigned j6 = cvtpk(p[12], p[13]), j7 = cvtpk(p[14], p[15]);

        uint32x2_t sA2 = __builtin_amdgcn_permlane32_swap(j0, j2, false, false);
        uint32x2_t sB2 = __builtin_amdgcn_permlane32_swap(j1, j3, false, false);
        union { unsigned u[4]; bf16x8 v; } P1;
        P1.u[0] = sA2.x; P1.u[1] = sB2.x; P1.u[2] = sA2.y; P1.u[3] = sB2.y;
        uint32x2_t sC2 = __builtin_amdgcn_permlane32_swap(j4, j6, false, false);
        uint32x2_t sD2 = __builtin_amdgcn_permlane32_swap(j5, j7, false, false);
        union { unsigned u[4]; bf16x8 v; } P2;
        P2.u[0] = sC2.x; P2.u[1] = sD2.x; P2.u[2] = sC2.y; P2.u[3] = sD2.y;

        OA = __builtin_amdgcn_mfma_f32_32x32x16_bf16(V0, P1.v, OA, 0, 0, 0);
        OA = __builtin_amdgcn_mfma_f32_32x32x16_bf16(V1, P2.v, OA, 0, 0, 0);

        K0 = nK0; K1 = nK1;
        k0 = kn;
    }

    // ---- write private partials (plain stores, no atomics) ----
    lA += __shfl_xor(lA, 32, 64);        // halves hold disjoint keys
    size_t pbase = (size_t)(b * 16 + kt) * NN;
    if (h == 0) {
        lpart[pbase + qbase + q] = lA;
    }
    size_t oA = (pbase + qbase + q) * EE + 4 * h;        // e = 8*gi + 4h + r
#pragma unroll
    for (int gi = 0; gi < 4; ++gi) {
        uint2 pa;
        pa.x = cvtpk(OA[4*gi],   OA[4*gi+1]);
        pa.y = cvtpk(OA[4*gi+2], OA[4*gi+3]);
        *(uint2*)(part + oA + 8 * gi) = pa;
    }
}

// ---------------------------------------------------------------------------
// K2b: split-K reduce. thread = (query i, 8e-group): sum 16 kt partials,
// normalize by summed l, emit vT f32 [B][N][32].
// grid = B*N*4/256 = 256, block = 256.
// ---------------------------------------------------------------------------
__global__ __launch_bounds__(256) void reduce_kernel(
    const unsigned short* __restrict__ part, const float* __restrict__ lpart,
    float* __restrict__ vT)
{
    int blk = blockIdx.x;
    int b   = blk >> 6;
    int it  = blk & 63;
    int t   = threadIdx.x;
    int i   = it * 64 + (t >> 2);
    int g4  = t & 3;                 // 8-e group

    float l = 0.f;
    float acc[8];
#pragma unroll
    for (int r = 0; r < 8; ++r) acc[r] = 0.f;
#pragma unroll
    for (int kt = 0; kt < 16; ++kt) {
        size_t pbase = (size_t)(b * 16 + kt) * NN + i;
        l += lpart[pbase];
        uint4 u = *(const uint4*)(part + pbase * EE + g4 * 8);
        acc[0] += bflo(u.x); acc[1] += bfhi(u.x);
        acc[2] += bflo(u.y); acc[3] += bfhi(u.y);
        acc[4] += bflo(u.z); acc[5] += bfhi(u.z);
        acc[6] += bflo(u.w); acc[7] += bfhi(u.w);
    }
    float inv = 1.f / l;
    float* vp = vT + ((size_t)b * NN + i) * EE + g4 * 8;
    float4 o0 = make_float4(acc[0]*inv, acc[1]*inv, acc[2]*inv, acc[3]*inv);
    float4 o1 = make_float4(acc[4]*inv, acc[5]*inv, acc[6]*inv, acc[7]*inv);
    *(float4*)vp       = o0;
    *(float4*)(vp + 4) = o1;
}

// ---------------------------------------------------------------------------
// K3: output 1x1 conv + residual. vT is [B][N][32] f32 (contiguous per i).
// grid = B * 16 * 16 = 1024, block = 256 (16 co per thread).
// ---------------------------------------------------------------------------
__global__ __launch_bounds__(256) void out_kernel(
    const float* __restrict__ vT, const float* __restrict__ aw,
    const float* __restrict__ ab, const float* __restrict__ x,
    const float* __restrict__ gamma_p,
    float* __restrict__ y, float* __restrict__ o)
{
    int blk    = blockIdx.x;
    int csplit = blk & 15;
    int itile  = (blk >> 4) & 15;
    int b      = blk >> 8;
    int i      = itile * 256 + threadIdx.x;
    float gm   = gamma_p[0];

    const float4* vp4 = (const float4*)(vT + ((size_t)b * NN + i) * EE);
    float vr[EE];
#pragma unroll
    for (int u = 0; u < 8; ++u) {
        float4 t = vp4[u];
        vr[4*u+0] = t.x; vr[4*u+1] = t.y; vr[4*u+2] = t.z; vr[4*u+3] = t.w;
    }

    int co0 = csplit * 16;
#pragma unroll
    for (int co = co0; co < co0 + 16; ++co) {
        float s = ab[co];
#pragma unroll
        for (int e = 0; e < EE; ++e)
            s = fmaf(aw[co * EE + e], vr[e], s);
        size_t idx = ((size_t)b * CC + co) * NN + i;
        o[idx] = s;
        y[idx] = fmaf(gm, s, x[idx]);
    }
}

// ---------------------------------------------------------------------------
extern "C" void kernel_launch(void* const* d_in, const int* in_sizes, int n_in,
                              void* d_out, int out_size, void* d_ws, size_t ws_size,
                              hipStream_t stream)
{
    const float* x  = (const float*)d_in[0];
    const float* kw = (const float*)d_in[1];
    const float* kb = (const float*)d_in[2];
    const float* qw = (const float*)d_in[3];
    const float* qb = (const float*)d_in[4];
    const float* vw = (const float*)d_in[5];
    const float* vb = (const float*)d_in[6];
    const float* aw = (const float*)d_in[7];
    const float* ab = (const float*)d_in[8];
    const float* gm = (const float*)d_in[9];

    float* y = (float*)d_out;
    float* o = y + (size_t)BB * CC * NN;

    // ws: part bf16 [B*16][N][32] (16MB) | lpart f32 [B*16][N] (1MB) |
    //     vT f32 [B][N][32] (2MB) | bB f32 [128] | wB bf16 [96][256] |
    //     fT,gT bf16 [B][N][32] | hT bf16 tiled [B][N/32][32][32]
    unsigned short* part  = (unsigned short*)d_ws;
    float*          lpart = (float*)(part + (size_t)BB * 16 * NN * EE);
    float*          vT    = lpart + (size_t)BB * 16 * NN;
    float*          bB    = vT + (size_t)BB * NN * EE;
    __hip_bfloat16* wB    = (__hip_bfloat16*)(bB + 128);
    __hip_bfloat16* fT    = wB + 96 * 256;
    __hip_bfloat16* gT    = fT + (size_t)BB * NN * EE;
    __hip_bfloat16* hT    = gT + (size_t)BB * NN * EE;

    wcvt_kernel<<<96, 256, 0, stream>>>(kw, kb, qw, qb, vw, vb, wB, bB);
    proj_kernel<<<BB * (NN / 32), 256, 0, stream>>>(x, wB, bB, fT, gT, hT);
    attn_kernel<<<BB * 16 * 16, 512, 0, stream>>>(fT, gT, hT, part, lpart);
    reduce_kernel<<<BB * 64, 256, 0, stream>>>(part, lpart, vT);
    out_kernel<<<BB * 16 * 16, 256, 0, stream>>>(vT, aw, ab, x, gm, y, o);
}

// Round 19
// 58.087 us; speedup vs baseline: 1.0767x; 1.0767x over previous
//
#include <hip/hip_runtime.h>
#include <hip/hip_bf16.h>
#include <math.h>

#define BB 4
#define CC 256
#define NN 4096   // H*W
#define EE 32     // embedding channels

typedef __attribute__((ext_vector_type(8))) short bf16x8;    // 8 bf16 = 4 VGPR
typedef __attribute__((ext_vector_type(4))) float f32x4;
typedef __attribute__((ext_vector_type(16))) float f32x16;
typedef __attribute__((ext_vector_type(2))) unsigned uint32x2_t;

__device__ inline unsigned short f2bf(float x) {
    union { __hip_bfloat16 h; unsigned short u; } cv;
    cv.h = __float2bfloat16(x);
    return cv.u;
}
__device__ inline unsigned pk2(float lo, float hi) {
    return ((unsigned)f2bf(hi) << 16) | (unsigned)f2bf(lo);
}
__device__ inline float fexp2(float x) { return __builtin_amdgcn_exp2f(x); }
__device__ inline unsigned cvtpk(float lo, float hi) {
    unsigned r;
    asm("v_cvt_pk_bf16_f32 %0, %1, %2" : "=v"(r) : "v"(lo), "v"(hi));
    return r;
}
__device__ inline float bflo(unsigned u) {
    union { unsigned v; float f; } c; c.v = u << 16; return c.f;
}
__device__ inline float bfhi(unsigned u) {
    union { unsigned v; float f; } c; c.v = u & 0xFFFF0000u; return c.f;
}

// ---------------------------------------------------------------------------
// K0: one-time weight convert. wB rows 0-31 = kw, 32-63 = qw*log2e, 64-95 = vw.
// ---------------------------------------------------------------------------
__global__ __launch_bounds__(256) void wcvt_kernel(
    const float* __restrict__ kw, const float* __restrict__ kb,
    const float* __restrict__ qw, const float* __restrict__ qb,
    const float* __restrict__ vw, const float* __restrict__ vb,
    __hip_bfloat16* __restrict__ wB, float* __restrict__ bB)
{
    int r = blockIdx.x;            // 0..95
    int t = threadIdx.x;
    int rr = r & 31;
    const float* src; float scale = 1.f;
    if (r < 32)      src = kw;
    else if (r < 64) { src = qw; scale = 1.44269504f; }
    else             src = vw;
    if (t < 64) {
        float4 v = *(const float4*)(src + rr * 256 + t * 4);
        uint2 p;
        p.x = pk2(v.x * scale, v.y * scale);
        p.y = pk2(v.z * scale, v.w * scale);
        *(uint2*)((unsigned short*)wB + r * 256 + t * 4) = p;
    }
    if (r == 0 && t >= 64 && t < 160) {
        int e = t - 64;
        const float* bs = (e < 32) ? kb : ((e < 64) ? qb : vb);
        float sc = (e >= 32 && e < 64) ? 1.44269504f : 1.f;
        bB[e] = bs[e & 31] * sc;
    }
}

// ---------------------------------------------------------------------------
// K1: MFMA QKV projection (x read once, all 96 channels).
//   fT/gT: [B][N][32]   hT: TILED [B][N/32][32e][32k]
// grid = B*(N/32) = 512, block = 256.
// ---------------------------------------------------------------------------
__global__ __launch_bounds__(256) void proj_kernel(
    const float* __restrict__ x,
    const __hip_bfloat16* __restrict__ wB, const float* __restrict__ bB,
    __hip_bfloat16* __restrict__ fT, __hip_bfloat16* __restrict__ gT,
    __hip_bfloat16* __restrict__ hT)
{
    __shared__ unsigned xs[32][132];   // stride 132 u32: b128 reads conflict-free
    int b     = blockIdx.x >> 7;
    int ibase = (blockIdx.x & 127) << 5;

    // staging: thread t loads x[c][i4..i4+3] for 8 c-pairs (coalesced float4)
    int t   = threadIdx.x;
    int ig4 = (t & 7) * 4;          // i offset 0..28
    int crw = t >> 3;               // c-row slot 0..31
    const float* xb = x + (size_t)b * CC * NN + ibase;
#pragma unroll
    for (int it = 0; it < 4; ++it) {
        int cp = it * 32 + crw;     // c-pair 0..127
        float4 fa = *(const float4*)(xb + (size_t)(2 * cp) * NN + ig4);
        float4 fc = *(const float4*)(xb + (size_t)(2 * cp + 1) * NN + ig4);
        xs[ig4 + 0][cp] = pk2(fa.x, fc.x);
        xs[ig4 + 1][cp] = pk2(fa.y, fc.y);
        xs[ig4 + 2][cp] = pk2(fa.z, fc.z);
        xs[ig4 + 3][cp] = pk2(fa.w, fc.w);
    }
    __syncthreads();

    int wv = threadIdx.x >> 6;
    int l  = threadIdx.x & 63;
    int q15  = l & 15, g = l >> 4;
    int isub = wv & 1, eh = wv >> 1;
    int irow = (isub << 4) + q15;
    const __hip_bfloat16* w0 = wB + ((size_t)(eh * 48) + q15) * 256;

    f32x4 a0 = {0,0,0,0}, a1 = {0,0,0,0}, a2 = {0,0,0,0};
#pragma unroll
    for (int kk = 0; kk < 8; ++kk) {
        bf16x8 Bf = *(const bf16x8*)&xs[irow][kk * 16 + 4 * g];
        int co = kk * 32 + 8 * g;
        bf16x8 A0 = *(const bf16x8*)(w0 + co);
        bf16x8 A1 = *(const bf16x8*)(w0 + 16 * 256 + co);
        bf16x8 A2 = *(const bf16x8*)(w0 + 32 * 256 + co);
        a0 = __builtin_amdgcn_mfma_f32_16x16x32_bf16(A0, Bf, a0, 0, 0, 0);
        a1 = __builtin_amdgcn_mfma_f32_16x16x32_bf16(A1, Bf, a1, 0, 0, 0);
        a2 = __builtin_amdgcn_mfma_f32_16x16x32_bf16(A2, Bf, a2, 0, 0, 0);
    }

    int ig = ibase + irow;
    auto emit = [&](f32x4 acc, int T) {
        float4 bb = *(const float4*)(bB + T * 16 + 4 * g);
        float d0 = acc[0] + bb.x, d1 = acc[1] + bb.y;
        float d2 = acc[2] + bb.z, d3 = acc[3] + bb.w;
        if (T < 4) {
            __hip_bfloat16* dst = (T < 2) ? fT : gT;
            int eoff = ((T & 1) << 4) + 4 * g;
            uint2 pq; pq.x = pk2(d0, d1); pq.y = pk2(d2, d3);
            *(uint2*)((unsigned short*)dst + ((size_t)b * NN + ig) * EE + eoff) = pq;
        } else {
            unsigned short* dst = (unsigned short*)hT;
            int e  = ((T - 4) << 4) + 4 * g;
            int kt = ig >> 5, kk2 = ig & 31;
            size_t base = ((size_t)(b * 128 + kt) * 32 + e) * 32 + kk2;
            dst[base]       = f2bf(d0);
            dst[base + 32]  = f2bf(d1);
            dst[base + 64]  = f2bf(d2);
            dst[base + 96]  = f2bf(d3);
        }
    };
    emit(a0, eh * 3 + 0);
    emit(a1, eh * 3 + 1);
    emit(a2, eh * 3 + 2);
}

// ---------------------------------------------------------------------------
// K2: attention pass 1 (split-K). NO setprio (r14 A/B: every wave at prio1
// defeated CU wave arbitration) and the 4 S MFMAs are independent (no
// C-chain); halves VALU-added at exp time.  (r18's depth-2 ring reverted:
// unexplained miscompile-level failure at ~160 live VGPRs under the 128 cap.)
// Block = 512 queries x 256 keys: 8 waves share one 32KB K/V slice (L1),
// each wave 64 queries (2 q-sets). Fixed m=0 softmax -> pure-sum partials,
// plain coalesced stores. part: [B*16kt][N][32] bf16  lpart: [B*16kt][N] f32
// grid = B * 8qt * 16kt = 512, block = 512, 4 waves/EU.
// ---------------------------------------------------------------------------
__global__ __launch_bounds__(512, 4) void attn_kernel(
    const __hip_bfloat16* __restrict__ fT,
    const __hip_bfloat16* __restrict__ gT,
    const __hip_bfloat16* __restrict__ hT,
    unsigned short* __restrict__ part, float* __restrict__ lpart)
{
    int blk   = blockIdx.x;
    int b     = blk >> 7;
    int qt    = (blk >> 4) & 7;      // query tile (512 q)
    int kt    = blk & 15;            // key tile (256 k)
    int wv    = threadIdx.x >> 6;    // q-subtile 0..7
    int lane  = threadIdx.x & 63;
    int q     = lane & 31;
    int h     = lane >> 5;           // key-half
    int qbase = qt * 512 + wv * 64;

    const __hip_bfloat16* fb = fT + (size_t)b * NN * EE;
    const __hip_bfloat16* gb = gT + (size_t)b * NN * EE;
    const __hip_bfloat16* hb = hT + (size_t)b * NN * EE + q * 32 + 8 * h; // e=q

    bf16x8 Qa0 = *(const bf16x8*)(gb + (size_t)(qbase + q) * EE + 8 * h);
    bf16x8 Qa1 = *(const bf16x8*)(gb + (size_t)(qbase + q) * EE + 16 + 8 * h);
    bf16x8 Qb0 = *(const bf16x8*)(gb + (size_t)(qbase + 32 + q) * EE + 8 * h);
    bf16x8 Qb1 = *(const bf16x8*)(gb + (size_t)(qbase + 32 + q) * EE + 16 + 8 * h);

    float lA = 0.f, lB = 0.f;
    f32x16 OA = {0,0,0,0,0,0,0,0,0,0,0,0,0,0,0,0};
    f32x16 OB = {0,0,0,0,0,0,0,0,0,0,0,0,0,0,0,0};
    const f32x16 z16 = {0,0,0,0,0,0,0,0,0,0,0,0,0,0,0,0};

    int k0 = kt * 256;
    bf16x8 K0 = *(const bf16x8*)(fb + (size_t)(k0 + q) * EE + 8 * h);
    bf16x8 K1 = *(const bf16x8*)(fb + (size_t)(k0 + q) * EE + 16 + 8 * h);
    bf16x8 V0 = *(const bf16x8*)(hb + (size_t)k0 * 32);
    bf16x8 V1 = *(const bf16x8*)(hb + (size_t)k0 * 32 + 16);

    for (int c = 0; c < 8; ++c) {
        int kn = (k0 + 32) & (NN - 1);   // last prefetch clamped into range
        bf16x8 nK0 = *(const bf16x8*)(fb + (size_t)(kn + q) * EE + 8 * h);
        bf16x8 nK1 = *(const bf16x8*)(fb + (size_t)(kn + q) * EE + 16 + 8 * h);
        bf16x8 nV0 = *(const bf16x8*)(hb + (size_t)kn * 32);
        bf16x8 nV1 = *(const bf16x8*)(hb + (size_t)kn * 32 + 16);

        // independent S halves (no MFMA C-chain); VALU-add at exp time
        f32x16 SA0 = __builtin_amdgcn_mfma_f32_32x32x16_bf16(K0, Qa0, z16, 0, 0, 0);
        f32x16 SA1 = __builtin_amdgcn_mfma_f32_32x32x16_bf16(K1, Qa1, z16, 0, 0, 0);
        f32x16 SB0 = __builtin_amdgcn_mfma_f32_32x32x16_bf16(K0, Qb0, z16, 0, 0, 0);
        f32x16 SB1 = __builtin_amdgcn_mfma_f32_32x32x16_bf16(K1, Qb1, z16, 0, 0, 0);

        {   // ---- q-set A softmax + PV ----
            float p[16];
#pragma unroll
            for (int r = 0; r < 16; ++r) p[r] = fexp2(SA0[r] + SA1[r]);
            lA += ((p[0]+p[1])+(p[2]+p[3])) + ((p[4]+p[5])+(p[6]+p[7]))
                + ((p[8]+p[9])+(p[10]+p[11])) + ((p[12]+p[13])+(p[14]+p[15]));
            unsigned j0 = cvtpk(p[0], p[1]),   j1 = cvtpk(p[2], p[3]);
            unsigned j2 = cvtpk(p[4], p[5]),   j3 = cvtpk(p[6], p[7]);
            unsigned j4 = cvtpk(p[8], p[9]),   j5 = cvtpk(p[10], p[11]);
            unsigned j6 = cvtpk(p[12], p[13]), j7 = cvtpk(p[14], p[15]);
            uint32x2_t sA2 = __builtin_amdgcn_permlane32_swap(j0, j2, false, false);
            uint32x2_t sB2 = __builtin_amdgcn_permlane32_swap(j1, j3, false, false);
            union { unsigned u[4]; bf16x8 v; } P1;
            P1.u[0] = sA2.x; P1.u[1] = sB2.x; P1.u[2] = sA2.y; P1.u[3] = sB2.y;
            uint32x2_t sC2 = __builtin_amdgcn_permlane32_swap(j4, j6, false, false);
            uint32x2_t sD2 = __builtin_amdgcn_permlane32_swap(j5, j7, false, false);
            union { unsigned u[4]; bf16x8 v; } P2;
            P2.u[0] = sC2.x; P2.u[1] = sD2.x; P2.u[2] = sC2.y; P2.u[3] = sD2.y;
            OA = __builtin_amdgcn_mfma_f32_32x32x16_bf16(V0, P1.v, OA, 0, 0, 0);
            OA = __builtin_amdgcn_mfma_f32_32x32x16_bf16(V1, P2.v, OA, 0, 0, 0);
        }

        {   // ---- q-set B softmax + PV ----
            float p[16];
#pragma unroll
            for (int r = 0; r < 16; ++r) p[r] = fexp2(SB0[r] + SB1[r]);
            lB += ((p[0]+p[1])+(p[2]+p[3])) + ((p[4]+p[5])+(p[6]+p[7]))
                + ((p[8]+p[9])+(p[10]+p[11])) + ((p[12]+p[13])+(p[14]+p[15]));
            unsigned j0 = cvtpk(p[0], p[1]),   j1 = cvtpk(p[2], p[3]);
            unsigned j2 = cvtpk(p[4], p[5]),   j3 = cvtpk(p[6], p[7]);
            unsigned j4 = cvtpk(p[8], p[9]),   j5 = cvtpk(p[10], p[11]);
            unsigned j6 = cvtpk(p[12], p[13]), j7 = cvtpk(p[14], p[15]);
            uint32x2_t sA2 = __builtin_amdgcn_permlane32_swap(j0, j2, false, false);
            uint32x2_t sB2 = __builtin_amdgcn_permlane32_swap(j1, j3, false, false);
            union { unsigned u[4]; bf16x8 v; } P1;
            P1.u[0] = sA2.x; P1.u[1] = sB2.x; P1.u[2] = sA2.y; P1.u[3] = sB2.y;
            uint32x2_t sC2 = __builtin_amdgcn_permlane32_swap(j4, j6, false, false);
            uint32x2_t sD2 = __builtin_amdgcn_permlane32_swap(j5, j7, false, false);
            union { unsigned u[4]; bf16x8 v; } P2;
            P2.u[0] = sC2.x; P2.u[1] = sD2.x; P2.u[2] = sC2.y; P2.u[3] = sD2.y;
            OB = __builtin_amdgcn_mfma_f32_32x32x16_bf16(V0, P1.v, OB, 0, 0, 0);
            OB = __builtin_amdgcn_mfma_f32_32x32x16_bf16(V1, P2.v, OB, 0, 0, 0);
        }

        K0 = nK0; K1 = nK1; V0 = nV0; V1 = nV1;
        k0 = kn;
    }

    // ---- write private partials (plain stores, no atomics) ----
    lA += __shfl_xor(lA, 32, 64);        // halves hold disjoint keys
    lB += __shfl_xor(lB, 32, 64);
    size_t pbase = (size_t)(b * 16 + kt) * NN;
    if (h == 0) {
        float* lp = lpart + pbase + qbase;
        lp[q]      = lA;
        lp[32 + q] = lB;
    }
    size_t oA = (pbase + qbase + q) * EE + 4 * h;        // e = 8*gi + 4h + r
    size_t oB = (pbase + qbase + 32 + q) * EE + 4 * h;
#pragma unroll
    for (int gi = 0; gi < 4; ++gi) {
        uint2 pa, pb;
        pa.x = cvtpk(OA[4*gi],   OA[4*gi+1]);
        pa.y = cvtpk(OA[4*gi+2], OA[4*gi+3]);
        pb.x = cvtpk(OB[4*gi],   OB[4*gi+1]);
        pb.y = cvtpk(OB[4*gi+2], OB[4*gi+3]);
        *(uint2*)(part + oA + 8 * gi) = pa;
        *(uint2*)(part + oB + 8 * gi) = pb;
    }
}

// ---------------------------------------------------------------------------
// K2b: split-K reduce. thread = (query i, 8e-group): sum 16 kt partials,
// normalize by summed l, emit vT f32 [B][N][32].
// Re-gridded for TLP: 512 blocks x 128 thr (2 blocks/CU vs 1 before).
// grid = B*128 = 512, block = 128.
// ---------------------------------------------------------------------------
__global__ __launch_bounds__(128) void reduce_kernel(
    const unsigned short* __restrict__ part, const float* __restrict__ lpart,
    float* __restrict__ vT)
{
    int blk = blockIdx.x;
    int b   = blk >> 7;
    int it  = blk & 127;
    int t   = threadIdx.x;
    int i   = it * 32 + (t >> 2);
    int g4  = t & 3;                 // 8-e group

    float l = 0.f;
    float acc[8];
#pragma unroll
    for (int r = 0; r < 8; ++r) acc[r] = 0.f;
#pragma unroll
    for (int kt = 0; kt < 16; ++kt) {
        size_t pbase = (size_t)(b * 16 + kt) * NN + i;
        l += lpart[pbase];
        uint4 u = *(const uint4*)(part + pbase * EE + g4 * 8);
        acc[0] += bflo(u.x); acc[1] += bfhi(u.x);
        acc[2] += bflo(u.y); acc[3] += bfhi(u.y);
        acc[4] += bflo(u.z); acc[5] += bfhi(u.z);
        acc[6] += bflo(u.w); acc[7] += bfhi(u.w);
    }
    float inv = 1.f / l;
    float* vp = vT + ((size_t)b * NN + i) * EE + g4 * 8;
    float4 o0 = make_float4(acc[0]*inv, acc[1]*inv, acc[2]*inv, acc[3]*inv);
    float4 o1 = make_float4(acc[4]*inv, acc[5]*inv, acc[6]*inv, acc[7]*inv);
    *(float4*)vp       = o0;
    *(float4*)(vp + 4) = o1;
}

// ---------------------------------------------------------------------------
// K3: output 1x1 conv + residual. vT is [B][N][32] f32 (contiguous per i).
// grid = B * 16 * 16 = 1024, block = 256 (16 co per thread).
// ---------------------------------------------------------------------------
__global__ __launch_bounds__(256) void out_kernel(
    const float* __restrict__ vT, const float* __restrict__ aw,
    const float* __restrict__ ab, const float* __restrict__ x,
    const float* __restrict__ gamma_p,
    float* __restrict__ y, float* __restrict__ o)
{
    int blk    = blockIdx.x;
    int csplit = blk & 15;
    int itile  = (blk >> 4) & 15;
    int b      = blk >> 8;
    int i      = itile * 256 + threadIdx.x;
    float gm   = gamma_p[0];

    const float4* vp4 = (const float4*)(vT + ((size_t)b * NN + i) * EE);
    float vr[EE];
#pragma unroll
    for (int u = 0; u < 8; ++u) {
        float4 t = vp4[u];
        vr[4*u+0] = t.x; vr[4*u+1] = t.y; vr[4*u+2] = t.z; vr[4*u+3] = t.w;
    }

    int co0 = csplit * 16;
#pragma unroll
    for (int co = co0; co < co0 + 16; ++co) {
        float s = ab[co];
#pragma unroll
        for (int e = 0; e < EE; ++e)
            s = fmaf(aw[co * EE + e], vr[e], s);
        size_t idx = ((size_t)b * CC + co) * NN + i;
        o[idx] = s;
        y[idx] = fmaf(gm, s, x[idx]);
    }
}

// ---------------------------------------------------------------------------
extern "C" void kernel_launch(void* const* d_in, const int* in_sizes, int n_in,
                              void* d_out, int out_size, void* d_ws, size_t ws_size,
                              hipStream_t stream)
{
    const float* x  = (const float*)d_in[0];
    const float* kw = (const float*)d_in[1];
    const float* kb = (const float*)d_in[2];
    const float* qw = (const float*)d_in[3];
    const float* qb = (const float*)d_in[4];
    const float* vw = (const float*)d_in[5];
    const float* vb = (const float*)d_in[6];
    const float* aw = (const float*)d_in[7];
    const float* ab = (const float*)d_in[8];
    const float* gm = (const float*)d_in[9];

    float* y = (float*)d_out;
    float* o = y + (size_t)BB * CC * NN;

    // ws: part bf16 [B*16][N][32] (16MB) | lpart f32 [B*16][N] (1MB) |
    //     vT f32 [B][N][32] (2MB) | bB f32 [128] | wB bf16 [96][256] |
    //     fT,gT bf16 [B][N][32] | hT bf16 tiled [B][N/32][32][32]
    unsigned short* part  = (unsigned short*)d_ws;
    float*          lpart = (float*)(part + (size_t)BB * 16 * NN * EE);
    float*          vT    = lpart + (size_t)BB * 16 * NN;
    float*          bB    = vT + (size_t)BB * NN * EE;
    __hip_bfloat16* wB    = (__hip_bfloat16*)(bB + 128);
    __hip_bfloat16* fT    = wB + 96 * 256;
    __hip_bfloat16* gT    = fT + (size_t)BB * NN * EE;
    __hip_bfloat16* hT    = gT + (size_t)BB * NN * EE;

    wcvt_kernel<<<96, 256, 0, stream>>>(kw, kb, qw, qb, vw, vb, wB, bB);
    proj_kernel<<<BB * (NN / 32), 256, 0, stream>>>(x, wB, bB, fT, gT, hT);
    attn_kernel<<<BB * 8 * 16, 512, 0, stream>>>(fT, gT, hT, part, lpart);
    reduce_kernel<<<BB * 128, 128, 0, stream>>>(part, lpart, vT);
    out_kernel<<<BB * 16 * 16, 256, 0, stream>>>(vT, aw, ab, x, gm, y, o);
}

// Round 20
// 56.904 us; speedup vs baseline: 1.0991x; 1.0208x over previous
//
#include <hip/hip_runtime.h>
#include <hip/hip_bf16.h>
#include <math.h>

#define BB 4
#define CC 256
#define NN 4096   // H*W
#define EE 32     // embedding channels

typedef __attribute__((ext_vector_type(8))) short bf16x8;    // 8 bf16 = 4 VGPR
typedef __attribute__((ext_vector_type(4))) float f32x4;
typedef __attribute__((ext_vector_type(16))) float f32x16;
typedef __attribute__((ext_vector_type(2))) unsigned uint32x2_t;

__device__ inline unsigned short f2bf(float x) {
    union { __hip_bfloat16 h; unsigned short u; } cv;
    cv.h = __float2bfloat16(x);
    return cv.u;
}
__device__ inline unsigned pk2(float lo, float hi) {
    return ((unsigned)f2bf(hi) << 16) | (unsigned)f2bf(lo);
}
__device__ inline float fexp2(float x) { return __builtin_amdgcn_exp2f(x); }
__device__ inline unsigned cvtpk(float lo, float hi) {
    unsigned r;
    asm("v_cvt_pk_bf16_f32 %0, %1, %2" : "=v"(r) : "v"(lo), "v"(hi));
    return r;
}
__device__ inline float bflo(unsigned u) {
    union { unsigned v; float f; } c; c.v = u << 16; return c.f;
}
__device__ inline float bfhi(unsigned u) {
    union { unsigned v; float f; } c; c.v = u & 0xFFFF0000u; return c.f;
}

// ---------------------------------------------------------------------------
// K0: one-time weight convert. wB rows 0-31 = kw, 32-63 = qw*log2e, 64-95 = vw.
// ---------------------------------------------------------------------------
__global__ __launch_bounds__(256) void wcvt_kernel(
    const float* __restrict__ kw, const float* __restrict__ kb,
    const float* __restrict__ qw, const float* __restrict__ qb,
    const float* __restrict__ vw, const float* __restrict__ vb,
    __hip_bfloat16* __restrict__ wB, float* __restrict__ bB)
{
    int r = blockIdx.x;            // 0..95
    int t = threadIdx.x;
    int rr = r & 31;
    const float* src; float scale = 1.f;
    if (r < 32)      src = kw;
    else if (r < 64) { src = qw; scale = 1.44269504f; }
    else             src = vw;
    if (t < 64) {
        float4 v = *(const float4*)(src + rr * 256 + t * 4);
        uint2 p;
        p.x = pk2(v.x * scale, v.y * scale);
        p.y = pk2(v.z * scale, v.w * scale);
        *(uint2*)((unsigned short*)wB + r * 256 + t * 4) = p;
    }
    if (r == 0 && t >= 64 && t < 160) {
        int e = t - 64;
        const float* bs = (e < 32) ? kb : ((e < 64) ? qb : vb);
        float sc = (e >= 32 && e < 64) ? 1.44269504f : 1.f;
        bB[e] = bs[e & 31] * sc;
    }
}

// ---------------------------------------------------------------------------
// K1: MFMA QKV projection (x read once, all 96 channels).
//   fT/gT: [B][N][32]   hT: TILED [B][N/32][32e][32k]
// grid = B*(N/32) = 512, block = 256.
// ---------------------------------------------------------------------------
__global__ __launch_bounds__(256) void proj_kernel(
    const float* __restrict__ x,
    const __hip_bfloat16* __restrict__ wB, const float* __restrict__ bB,
    __hip_bfloat16* __restrict__ fT, __hip_bfloat16* __restrict__ gT,
    __hip_bfloat16* __restrict__ hT)
{
    __shared__ unsigned xs[32][132];   // stride 132 u32: b128 reads conflict-free
    int b     = blockIdx.x >> 7;
    int ibase = (blockIdx.x & 127) << 5;

    // staging: thread t loads x[c][i4..i4+3] for 8 c-pairs (coalesced float4)
    int t   = threadIdx.x;
    int ig4 = (t & 7) * 4;          // i offset 0..28
    int crw = t >> 3;               // c-row slot 0..31
    const float* xb = x + (size_t)b * CC * NN + ibase;
#pragma unroll
    for (int it = 0; it < 4; ++it) {
        int cp = it * 32 + crw;     // c-pair 0..127
        float4 fa = *(const float4*)(xb + (size_t)(2 * cp) * NN + ig4);
        float4 fc = *(const float4*)(xb + (size_t)(2 * cp + 1) * NN + ig4);
        xs[ig4 + 0][cp] = pk2(fa.x, fc.x);
        xs[ig4 + 1][cp] = pk2(fa.y, fc.y);
        xs[ig4 + 2][cp] = pk2(fa.z, fc.z);
        xs[ig4 + 3][cp] = pk2(fa.w, fc.w);
    }
    __syncthreads();

    int wv = threadIdx.x >> 6;
    int l  = threadIdx.x & 63;
    int q15  = l & 15, g = l >> 4;
    int isub = wv & 1, eh = wv >> 1;
    int irow = (isub << 4) + q15;
    const __hip_bfloat16* w0 = wB + ((size_t)(eh * 48) + q15) * 256;

    f32x4 a0 = {0,0,0,0}, a1 = {0,0,0,0}, a2 = {0,0,0,0};
#pragma unroll
    for (int kk = 0; kk < 8; ++kk) {
        bf16x8 Bf = *(const bf16x8*)&xs[irow][kk * 16 + 4 * g];
        int co = kk * 32 + 8 * g;
        bf16x8 A0 = *(const bf16x8*)(w0 + co);
        bf16x8 A1 = *(const bf16x8*)(w0 + 16 * 256 + co);
        bf16x8 A2 = *(const bf16x8*)(w0 + 32 * 256 + co);
        a0 = __builtin_amdgcn_mfma_f32_16x16x32_bf16(A0, Bf, a0, 0, 0, 0);
        a1 = __builtin_amdgcn_mfma_f32_16x16x32_bf16(A1, Bf, a1, 0, 0, 0);
        a2 = __builtin_amdgcn_mfma_f32_16x16x32_bf16(A2, Bf, a2, 0, 0, 0);
    }

    int ig = ibase + irow;
    auto emit = [&](f32x4 acc, int T) {
        float4 bb = *(const float4*)(bB + T * 16 + 4 * g);
        float d0 = acc[0] + bb.x, d1 = acc[1] + bb.y;
        float d2 = acc[2] + bb.z, d3 = acc[3] + bb.w;
        if (T < 4) {
            __hip_bfloat16* dst = (T < 2) ? fT : gT;
            int eoff = ((T & 1) << 4) + 4 * g;
            uint2 pq; pq.x = pk2(d0, d1); pq.y = pk2(d2, d3);
            *(uint2*)((unsigned short*)dst + ((size_t)b * NN + ig) * EE + eoff) = pq;
        } else {
            unsigned short* dst = (unsigned short*)hT;
            int e  = ((T - 4) << 4) + 4 * g;
            int kt = ig >> 5, kk2 = ig & 31;
            size_t base = ((size_t)(b * 128 + kt) * 32 + e) * 32 + kk2;
            dst[base]       = f2bf(d0);
            dst[base + 32]  = f2bf(d1);
            dst[base + 64]  = f2bf(d2);
            dst[base + 96]  = f2bf(d3);
        }
    };
    emit(a0, eh * 3 + 0);
    emit(a1, eh * 3 + 1);
    emit(a2, eh * 3 + 2);
}

// ---------------------------------------------------------------------------
// K2: attention pass 1 (split-K), LDS-STAGED K/V: the block's 256-key slice
// (32KB) is staged into LDS ONCE, cooperatively (wave wv stages chunk wv
// using the exact per-lane global addresses of the old loop, written to
// fragment-major kbuf/vbuf[16][64] -- lane-contiguous 16B slots, conflict-
// free b128 both directions). The 8-chunk loop then reads LDS (~120cy) in
// place of L2/HBM round-trips (~900cy first touch, ~6 loads in flight) that
// wall-clock arithmetic says serialized the loop. Inner math unchanged.
// NO setprio (r14); independent S MFMAs (r14). Fixed m=0 softmax.
// part: [B*16kt][N][32] bf16  lpart: [B*16kt][N] f32
// grid = B * 8qt * 16kt = 512, block = 512, 4 waves/EU.
// ---------------------------------------------------------------------------
__global__ __launch_bounds__(512, 4) void attn_kernel(
    const __hip_bfloat16* __restrict__ fT,
    const __hip_bfloat16* __restrict__ gT,
    const __hip_bfloat16* __restrict__ hT,
    unsigned short* __restrict__ part, float* __restrict__ lpart)
{
    __shared__ bf16x8 kbuf[16][64];   // 16KB: K frags, slot (c*2+f), lane
    __shared__ bf16x8 vbuf[16][64];   // 16KB: V frags
    int blk   = blockIdx.x;
    int b     = blk >> 7;
    int qt    = (blk >> 4) & 7;      // query tile (512 q)
    int kt    = blk & 15;            // key tile (256 k)
    int wv    = threadIdx.x >> 6;    // q-subtile 0..7
    int lane  = threadIdx.x & 63;
    int q     = lane & 31;
    int h     = lane >> 5;           // key-half
    int qbase = qt * 512 + wv * 64;

    const __hip_bfloat16* fb = fT + (size_t)b * NN * EE;
    const __hip_bfloat16* gb = gT + (size_t)b * NN * EE;
    const __hip_bfloat16* hb = hT + (size_t)b * NN * EE + q * 32 + 8 * h; // e=q

    // ---- cooperative K/V staging: wave wv stages chunk wv ----
    {
        int k0 = kt * 256 + wv * 32;
        kbuf[wv * 2 + 0][lane] = *(const bf16x8*)(fb + (size_t)(k0 + q) * EE + 8 * h);
        kbuf[wv * 2 + 1][lane] = *(const bf16x8*)(fb + (size_t)(k0 + q) * EE + 16 + 8 * h);
        vbuf[wv * 2 + 0][lane] = *(const bf16x8*)(hb + (size_t)k0 * 32);
        vbuf[wv * 2 + 1][lane] = *(const bf16x8*)(hb + (size_t)k0 * 32 + 16);
    }

    bf16x8 Qa0 = *(const bf16x8*)(gb + (size_t)(qbase + q) * EE + 8 * h);
    bf16x8 Qa1 = *(const bf16x8*)(gb + (size_t)(qbase + q) * EE + 16 + 8 * h);
    bf16x8 Qb0 = *(const bf16x8*)(gb + (size_t)(qbase + 32 + q) * EE + 8 * h);
    bf16x8 Qb1 = *(const bf16x8*)(gb + (size_t)(qbase + 32 + q) * EE + 16 + 8 * h);

    float lA = 0.f, lB = 0.f;
    f32x16 OA = {0,0,0,0,0,0,0,0,0,0,0,0,0,0,0,0};
    f32x16 OB = {0,0,0,0,0,0,0,0,0,0,0,0,0,0,0,0};
    const f32x16 z16 = {0,0,0,0,0,0,0,0,0,0,0,0,0,0,0,0};

    __syncthreads();   // staging complete; buffers read-only below

    for (int c = 0; c < 8; ++c) {
        bf16x8 K0 = kbuf[c * 2 + 0][lane];
        bf16x8 K1 = kbuf[c * 2 + 1][lane];
        bf16x8 V0 = vbuf[c * 2 + 0][lane];
        bf16x8 V1 = vbuf[c * 2 + 1][lane];

        // independent S halves (no MFMA C-chain); VALU-add at exp time
        f32x16 SA0 = __builtin_amdgcn_mfma_f32_32x32x16_bf16(K0, Qa0, z16, 0, 0, 0);
        f32x16 SA1 = __builtin_amdgcn_mfma_f32_32x32x16_bf16(K1, Qa1, z16, 0, 0, 0);
        f32x16 SB0 = __builtin_amdgcn_mfma_f32_32x32x16_bf16(K0, Qb0, z16, 0, 0, 0);
        f32x16 SB1 = __builtin_amdgcn_mfma_f32_32x32x16_bf16(K1, Qb1, z16, 0, 0, 0);

        {   // ---- q-set A softmax + PV ----
            float p[16];
#pragma unroll
            for (int r = 0; r < 16; ++r) p[r] = fexp2(SA0[r] + SA1[r]);
            lA += ((p[0]+p[1])+(p[2]+p[3])) + ((p[4]+p[5])+(p[6]+p[7]))
                + ((p[8]+p[9])+(p[10]+p[11])) + ((p[12]+p[13])+(p[14]+p[15]));
            unsigned j0 = cvtpk(p[0], p[1]),   j1 = cvtpk(p[2], p[3]);
            unsigned j2 = cvtpk(p[4], p[5]),   j3 = cvtpk(p[6], p[7]);
            unsigned j4 = cvtpk(p[8], p[9]),   j5 = cvtpk(p[10], p[11]);
            unsigned j6 = cvtpk(p[12], p[13]), j7 = cvtpk(p[14], p[15]);
            uint32x2_t sA2 = __builtin_amdgcn_permlane32_swap(j0, j2, false, false);
            uint32x2_t sB2 = __builtin_amdgcn_permlane32_swap(j1, j3, false, false);
            union { unsigned u[4]; bf16x8 v; } P1;
            P1.u[0] = sA2.x; P1.u[1] = sB2.x; P1.u[2] = sA2.y; P1.u[3] = sB2.y;
            uint32x2_t sC2 = __builtin_amdgcn_permlane32_swap(j4, j6, false, false);
            uint32x2_t sD2 = __builtin_amdgcn_permlane32_swap(j5, j7, false, false);
            union { unsigned u[4]; bf16x8 v; } P2;
            P2.u[0] = sC2.x; P2.u[1] = sD2.x; P2.u[2] = sC2.y; P2.u[3] = sD2.y;
            OA = __builtin_amdgcn_mfma_f32_32x32x16_bf16(V0, P1.v, OA, 0, 0, 0);
            OA = __builtin_amdgcn_mfma_f32_32x32x16_bf16(V1, P2.v, OA, 0, 0, 0);
        }

        {   // ---- q-set B softmax + PV ----
            float p[16];
#pragma unroll
            for (int r = 0; r < 16; ++r) p[r] = fexp2(SB0[r] + SB1[r]);
            lB += ((p[0]+p[1])+(p[2]+p[3])) + ((p[4]+p[5])+(p[6]+p[7]))
                + ((p[8]+p[9])+(p[10]+p[11])) + ((p[12]+p[13])+(p[14]+p[15]));
            unsigned j0 = cvtpk(p[0], p[1]),   j1 = cvtpk(p[2], p[3]);
            unsigned j2 = cvtpk(p[4], p[5]),   j3 = cvtpk(p[6], p[7]);
            unsigned j4 = cvtpk(p[8], p[9]),   j5 = cvtpk(p[10], p[11]);
            unsigned j6 = cvtpk(p[12], p[13]), j7 = cvtpk(p[14], p[15]);
            uint32x2_t sA2 = __builtin_amdgcn_permlane32_swap(j0, j2, false, false);
            uint32x2_t sB2 = __builtin_amdgcn_permlane32_swap(j1, j3, false, false);
            union { unsigned u[4]; bf16x8 v; } P1;
            P1.u[0] = sA2.x; P1.u[1] = sB2.x; P1.u[2] = sA2.y; P1.u[3] = sB2.y;
            uint32x2_t sC2 = __builtin_amdgcn_permlane32_swap(j4, j6, false, false);
            uint32x2_t sD2 = __builtin_amdgcn_permlane32_swap(j5, j7, false, false);
            union { unsigned u[4]; bf16x8 v; } P2;
            P2.u[0] = sC2.x; P2.u[1] = sD2.x; P2.u[2] = sC2.y; P2.u[3] = sD2.y;
            OB = __builtin_amdgcn_mfma_f32_32x32x16_bf16(V0, P1.v, OB, 0, 0, 0);
            OB = __builtin_amdgcn_mfma_f32_32x32x16_bf16(V1, P2.v, OB, 0, 0, 0);
        }
    }

    // ---- write private partials (plain stores, no atomics) ----
    lA += __shfl_xor(lA, 32, 64);        // halves hold disjoint keys
    lB += __shfl_xor(lB, 32, 64);
    size_t pbase = (size_t)(b * 16 + kt) * NN;
    if (h == 0) {
        float* lp = lpart + pbase + qbase;
        lp[q]      = lA;
        lp[32 + q] = lB;
    }
    size_t oA = (pbase + qbase + q) * EE + 4 * h;        // e = 8*gi + 4h + r
    size_t oB = (pbase + qbase + 32 + q) * EE + 4 * h;
#pragma unroll
    for (int gi = 0; gi < 4; ++gi) {
        uint2 pa, pb;
        pa.x = cvtpk(OA[4*gi],   OA[4*gi+1]);
        pa.y = cvtpk(OA[4*gi+2], OA[4*gi+3]);
        pb.x = cvtpk(OB[4*gi],   OB[4*gi+1]);
        pb.y = cvtpk(OB[4*gi+2], OB[4*gi+3]);
        *(uint2*)(part + oA + 8 * gi) = pa;
        *(uint2*)(part + oB + 8 * gi) = pb;
    }
}

// ---------------------------------------------------------------------------
// K2b: split-K reduce. thread = (query i, 8e-group): sum 16 kt partials,
// normalize by summed l, emit vT f32 [B][N][32].
// grid = B*128 = 512, block = 128 (2 blocks/CU).
// ---------------------------------------------------------------------------
__global__ __launch_bounds__(128) void reduce_kernel(
    const unsigned short* __restrict__ part, const float* __restrict__ lpart,
    float* __restrict__ vT)
{
    int blk = blockIdx.x;
    int b   = blk >> 7;
    int it  = blk & 127;
    int t   = threadIdx.x;
    int i   = it * 32 + (t >> 2);
    int g4  = t & 3;                 // 8-e group

    float l = 0.f;
    float acc[8];
#pragma unroll
    for (int r = 0; r < 8; ++r) acc[r] = 0.f;
#pragma unroll
    for (int kt = 0; kt < 16; ++kt) {
        size_t pbase = (size_t)(b * 16 + kt) * NN + i;
        l += lpart[pbase];
        uint4 u = *(const uint4*)(part + pbase * EE + g4 * 8);
        acc[0] += bflo(u.x); acc[1] += bfhi(u.x);
        acc[2] += bflo(u.y); acc[3] += bfhi(u.y);
        acc[4] += bflo(u.z); acc[5] += bfhi(u.z);
        acc[6] += bflo(u.w); acc[7] += bfhi(u.w);
    }
    float inv = 1.f / l;
    float* vp = vT + ((size_t)b * NN + i) * EE + g4 * 8;
    float4 o0 = make_float4(acc[0]*inv, acc[1]*inv, acc[2]*inv, acc[3]*inv);
    float4 o1 = make_float4(acc[4]*inv, acc[5]*inv, acc[6]*inv, acc[7]*inv);
    *(float4*)vp       = o0;
    *(float4*)(vp + 4) = o1;
}

// ---------------------------------------------------------------------------
// K3: output 1x1 conv + residual. vT is [B][N][32] f32 (contiguous per i).
// grid = B * 16 * 16 = 1024, block = 256 (16 co per thread).
// ---------------------------------------------------------------------------
__global__ __launch_bounds__(256) void out_kernel(
    const float* __restrict__ vT, const float* __restrict__ aw,
    const float* __restrict__ ab, const float* __restrict__ x,
    const float* __restrict__ gamma_p,
    float* __restrict__ y, float* __restrict__ o)
{
    int blk    = blockIdx.x;
    int csplit = blk & 15;
    int itile  = (blk >> 4) & 15;
    int b      = blk >> 8;
    int i      = itile * 256 + threadIdx.x;
    float gm   = gamma_p[0];

    const float4* vp4 = (const float4*)(vT + ((size_t)b * NN + i) * EE);
    float vr[EE];
#pragma unroll
    for (int u = 0; u < 8; ++u) {
        float4 t = vp4[u];
        vr[4*u+0] = t.x; vr[4*u+1] = t.y; vr[4*u+2] = t.z; vr[4*u+3] = t.w;
    }

    int co0 = csplit * 16;
#pragma unroll
    for (int co = co0; co < co0 + 16; ++co) {
        float s = ab[co];
#pragma unroll
        for (int e = 0; e < EE; ++e)
            s = fmaf(aw[co * EE + e], vr[e], s);
        size_t idx = ((size_t)b * CC + co) * NN + i;
        o[idx] = s;
        y[idx] = fmaf(gm, s, x[idx]);
    }
}

// ---------------------------------------------------------------------------
extern "C" void kernel_launch(void* const* d_in, const int* in_sizes, int n_in,
                              void* d_out, int out_size, void* d_ws, size_t ws_size,
                              hipStream_t stream)
{
    const float* x  = (const float*)d_in[0];
    const float* kw = (const float*)d_in[1];
    const float* kb = (const float*)d_in[2];
    const float* qw = (const float*)d_in[3];
    const float* qb = (const float*)d_in[4];
    const float* vw = (const float*)d_in[5];
    const float* vb = (const float*)d_in[6];
    const float* aw = (const float*)d_in[7];
    const float* ab = (const float*)d_in[8];
    const float* gm = (const float*)d_in[9];

    float* y = (float*)d_out;
    float* o = y + (size_t)BB * CC * NN;

    // ws: part bf16 [B*16][N][32] (16MB) | lpart f32 [B*16][N] (1MB) |
    //     vT f32 [B][N][32] (2MB) | bB f32 [128] | wB bf16 [96][256] |
    //     fT,gT bf16 [B][N][32] | hT bf16 tiled [B][N/32][32][32]
    unsigned short* part  = (unsigned short*)d_ws;
    float*          lpart = (float*)(part + (size_t)BB * 16 * NN * EE);
    float*          vT    = lpart + (size_t)BB * 16 * NN;
    float*          bB    = vT + (size_t)BB * NN * EE;
    __hip_bfloat16* wB    = (__hip_bfloat16*)(bB + 128);
    __hip_bfloat16* fT    = wB + 96 * 256;
    __hip_bfloat16* gT    = fT + (size_t)BB * NN * EE;
    __hip_bfloat16* hT    = gT + (size_t)BB * NN * EE;

    wcvt_kernel<<<96, 256, 0, stream>>>(kw, kb, qw, qb, vw, vb, wB, bB);
    proj_kernel<<<BB * (NN / 32), 256, 0, stream>>>(x, wB, bB, fT, gT, hT);
    attn_kernel<<<BB * 8 * 16, 512, 0, stream>>>(fT, gT, hT, part, lpart);
    reduce_kernel<<<BB * 128, 128, 0, stream>>>(part, lpart, vT);
    out_kernel<<<BB * 16 * 16, 256, 0, stream>>>(vT, aw, ab, x, gm, y, o);
}